// Round 8
// baseline (726.178 us; speedup 1.0000x reference)
//
#include <hip/hip_runtime.h>

#define NN 50000
#define EE 250000
#define HD 128

typedef __attribute__((ext_vector_type(8))) short bf16x8;
typedef __attribute__((ext_vector_type(4))) float f32x4;
typedef _Float16 half4v __attribute__((ext_vector_type(4)));

__device__ inline short f2bf(float f) {
    unsigned u = __builtin_bit_cast(unsigned, f);
    unsigned r = u + 0x7fffu + ((u >> 16) & 1u);
    return (short)(r >> 16);
}
__device__ inline float bf2f(short h) {
    unsigned u = ((unsigned)(unsigned short)h) << 16;
    return __builtin_bit_cast(float, u);
}

// ---------------- CSR build (both graphs in one launch) ----------------
__global__ void hist2_kernel(const int* __restrict__ row1, const int* __restrict__ row2,
                             int* __restrict__ cnt) {
    int t = blockIdx.x * blockDim.x + threadIdx.x;
    if (t >= 2 * EE) return;
    int g = t >= EE;
    int e = t - g * EE;
    const int* row = g ? row2 : row1;
    atomicAdd(&cnt[g * NN + row[e]], 1);
}

__global__ __launch_bounds__(1024) void scan2_kernel(const int* __restrict__ cnt_all,
                                                     int* __restrict__ rp1,
                                                     int* __restrict__ rp2) {
    __shared__ int s[1024];
    const int* cnt = cnt_all + blockIdx.x * NN;
    int* rp = blockIdx.x ? rp2 : rp1;
    int tid = threadIdx.x;
    int c0 = 0;
    for (int base = 0; base < NN; base += 8192) {
        int v[8];
        int sum = 0;
        int i0 = base + tid * 8;
#pragma unroll
        for (int j = 0; j < 8; ++j) {
            int i = i0 + j;
            v[j] = (i < NN) ? cnt[i] : 0;
            sum += v[j];
        }
        s[tid] = sum;
        __syncthreads();
        for (int off = 1; off < 1024; off <<= 1) {
            int t2 = (tid >= off) ? s[tid - off] : 0;
            __syncthreads();
            s[tid] += t2;
            __syncthreads();
        }
        int excl = c0 + s[tid] - sum;
#pragma unroll
        for (int j = 0; j < 8; ++j) {
            int i = i0 + j;
            if (i < NN) rp[i] = excl;
            excl += v[j];
        }
        int tot = s[1023];
        __syncthreads();
        c0 += tot;
    }
    if (tid == 0) rp[NN] = c0;
}

__global__ void scatter2_kernel(const int* __restrict__ row1, const int* __restrict__ col1,
                                const float* __restrict__ val1, const int* __restrict__ row2,
                                const int* __restrict__ col2, const float* __restrict__ val2,
                                const int* __restrict__ rp1, const int* __restrict__ rp2,
                                int* __restrict__ cur, int* __restrict__ cols1_s,
                                float* __restrict__ vals1_s, int* __restrict__ cols2_s,
                                float* __restrict__ vals2_s) {
    int t = blockIdx.x * blockDim.x + threadIdx.x;
    if (t >= 2 * EE) return;
    int g = t >= EE;
    int e = t - g * EE;
    const int* row = g ? row2 : row1;
    const int* col = g ? col2 : col1;
    const float* val = g ? val2 : val1;
    const int* rp = g ? rp2 : rp1;
    int* cols_s = g ? cols2_s : cols1_s;
    float* vals_s = g ? vals2_s : vals1_s;
    int r = row[e];
    int p = atomicAdd(&cur[g * NN + r], 1);
    int d = rp[r] + p;
    cols_s[d] = col[e];
    vals_s[d] = val[e];
}

// ---------------- weight pack (all 10 sections in one launch) ----------------
__device__ inline void pack_one(const float* __restrict__ in, short* __restrict__ out,
                                int NCOL, int NKS, int lo, int t) {
    int lane = t & 63, f = t >> 6;
    int ks = f % NKS, ct = f / NKS;
    int nl = lane & 15, kg = lane >> 4;
    int c = ct * 16 + nl;
    bf16x8 o;
#pragma unroll
    for (int j = 0; j < 8; ++j) {
        int k = ks * 32 + kg * 8 + j;
        float v = in[k * NCOL + c];
        short h = f2bf(v);
        o[j] = lo ? f2bf(v - bf2f(h)) : h;
    }
    *(bf16x8*)(out + f * 512 + lane * 8) = o;
}

__global__ void pack_all_kernel(const float* __restrict__ L1w, short* __restrict__ W1p,
                                const float* __restrict__ L2w, short* __restrict__ W2p,
                                const float* __restrict__ Wg0, const float* __restrict__ Wg1,
                                const float* __restrict__ Wg2, const float* __restrict__ Wg3,
                                short* __restrict__ Wh0, short* __restrict__ Wl0,
                                short* __restrict__ Wh1, short* __restrict__ Wl1,
                                short* __restrict__ Wh2, short* __restrict__ Wl2,
                                short* __restrict__ Wh3, short* __restrict__ Wl3) {
    int t = blockIdx.x * 256 + threadIdx.x;
    if (t < 4096) {
        pack_one(L1w, W1p, 256, 4, 0, t);
    } else if (t < 12288) {
        pack_one(L2w, W2p, 256, 8, 0, t - 4096);
    } else if (t < 28672) {
        int u = t - 12288;
        int l = u >> 12;
        int lo = (u >> 11) & 1;
        int tt = u & 2047;
        const float* in = l == 0 ? Wg0 : l == 1 ? Wg1 : l == 2 ? Wg2 : Wg3;
        short* out = l == 0 ? (lo ? Wl0 : Wh0)
                   : l == 1 ? (lo ? Wl1 : Wh1)
                   : l == 2 ? (lo ? Wl2 : Wh2)
                            : (lo ? Wl3 : Wh3);
        pack_one(in, out, 128, 4, lo, tt);
    }
}

__global__ void cvt_w0_kernel(const float* __restrict__ in, _Float16* __restrict__ out) {
    int t = blockIdx.x * 256 + threadIdx.x;
    int i = t * 4;
    if (i >= NN * HD) return;
    float4 v = *(const float4*)(in + i);
    half4v h;
    h[0] = (_Float16)v.x;
    h[1] = (_Float16)v.y;
    h[2] = (_Float16)v.z;
    h[3] = (_Float16)v.w;
    *(half4v*)(out + i) = h;
}

// ---------------- SpMM layer-1: l2norm(relu(A @ W0h)), emits fp16 + bf16 ----
// 2 rows/wave, 32 lanes x fp16x4; edge loop unrolled x8 branch-free.
__global__ __launch_bounds__(256) void spmm_norm_kernel(
    const int* __restrict__ rp, const int* __restrict__ cols, const float* __restrict__ vals,
    const _Float16* __restrict__ xin, _Float16* __restrict__ xf,
    unsigned short* __restrict__ xh) {
    int r = (blockIdx.x * 256 + threadIdx.x) >> 5;
    int ln = threadIdx.x & 31;
    if (r >= NN) return;
    int beg = rp[r], end = rp[r + 1];
    float4 acc = make_float4(0.f, 0.f, 0.f, 0.f);
    for (int e = beg; e < end; e += 8) {
#pragma unroll
        for (int i = 0; i < 8; ++i) {
            int ei = e + i;
            int idx = ei < end ? ei : end - 1;
            int c = cols[idx];
            float v = ei < end ? vals[idx] : 0.f;
            half4v xr = *(const half4v*)(xin + (size_t)c * HD + ln * 4);
            acc.x = fmaf(v, (float)xr[0], acc.x);
            acc.y = fmaf(v, (float)xr[1], acc.y);
            acc.z = fmaf(v, (float)xr[2], acc.z);
            acc.w = fmaf(v, (float)xr[3], acc.w);
        }
    }
    acc.x = fmaxf(acc.x, 0.f);
    acc.y = fmaxf(acc.y, 0.f);
    acc.z = fmaxf(acc.z, 0.f);
    acc.w = fmaxf(acc.w, 0.f);
    float ss = acc.x * acc.x + acc.y * acc.y + acc.z * acc.z + acc.w * acc.w;
#pragma unroll
    for (int off = 1; off < 32; off <<= 1) ss += __shfl_xor(ss, off, 64);
    float sc = 1.f / fmaxf(sqrtf(ss), 1e-12f);
    acc.x *= sc;
    acc.y *= sc;
    acc.z *= sc;
    acc.w *= sc;
    half4v hf;
    hf[0] = (_Float16)acc.x;
    hf[1] = (_Float16)acc.y;
    hf[2] = (_Float16)acc.z;
    hf[3] = (_Float16)acc.w;
    *(half4v*)(xf + (size_t)r * HD + ln * 4) = hf;
    short4 hs;
    hs.x = f2bf(acc.x);
    hs.y = f2bf(acc.y);
    hs.z = f2bf(acc.z);
    hs.w = f2bf(acc.w);
    *(short4*)(xh + (size_t)r * HD + ln * 4) = hs;
}

// ---------------- SpMM raw: z = A @ xf16, split bf16 (zh + zl) ----------------
__global__ __launch_bounds__(256) void spmm_raw_kernel(
    const int* __restrict__ rp, const int* __restrict__ cols, const float* __restrict__ vals,
    const _Float16* __restrict__ xin, short* __restrict__ zh, short* __restrict__ zl) {
    int r = (blockIdx.x * 256 + threadIdx.x) >> 5;
    int ln = threadIdx.x & 31;
    if (r >= NN) return;
    int beg = rp[r], end = rp[r + 1];
    float4 acc = make_float4(0.f, 0.f, 0.f, 0.f);
    for (int e = beg; e < end; e += 8) {
#pragma unroll
        for (int i = 0; i < 8; ++i) {
            int ei = e + i;
            int idx = ei < end ? ei : end - 1;
            int c = cols[idx];
            float v = ei < end ? vals[idx] : 0.f;
            half4v xr = *(const half4v*)(xin + (size_t)c * HD + ln * 4);
            acc.x = fmaf(v, (float)xr[0], acc.x);
            acc.y = fmaf(v, (float)xr[1], acc.y);
            acc.z = fmaf(v, (float)xr[2], acc.z);
            acc.w = fmaf(v, (float)xr[3], acc.w);
        }
    }
    short4 hh, hl;
    hh.x = f2bf(acc.x);
    hl.x = f2bf(acc.x - bf2f(hh.x));
    hh.y = f2bf(acc.y);
    hl.y = f2bf(acc.y - bf2f(hh.y));
    hh.z = f2bf(acc.z);
    hl.z = f2bf(acc.z - bf2f(hh.z));
    hh.w = f2bf(acc.w);
    hl.w = f2bf(acc.w - bf2f(hh.w));
    *(short4*)(zh + (size_t)r * HD + ln * 4) = hh;
    *(short4*)(zl + (size_t)r * HD + ln * 4) = hl;
}

// ---------------- fused GEMM + MLP ----------------
// 64 nodes/block, 4 waves. GEMM: x = [l2norm](relu(z @ W)) (split-bf16, ct-split
// 2/wave); x-tile -> swizzled LDS + fp16 global. MLP: A1 from LDS, H1 in LDS
// (ALIASED with Xt via union — never live simultaneously), layer2+3 fused dot.
// LDS 34.8KB -> 4 blocks/CU.
__global__ __launch_bounds__(256, 2) void gemm_mlp_kernel(
    const short* __restrict__ zh, const short* __restrict__ zl, const short* __restrict__ Wh,
    const short* __restrict__ Wl, const short* __restrict__ W1p, const float* __restrict__ L1b,
    const short* __restrict__ W2p, const float* __restrict__ L2b,
    const float* __restrict__ L3w, const float* __restrict__ L3b,
    _Float16* __restrict__ xfout, float* __restrict__ score, int do_norm, int write_x) {
    __shared__ __align__(16) char U[32768];  // Xt (16KB) then reused as H1s (32KB)
    __shared__ float redss[4][64];
    __shared__ float red[4][64];
    char* Xt = U;
    char* H1s = U;
    int tid = threadIdx.x;
    int wave = tid >> 6, lane = tid & 63;
    int nl = lane & 15, kg = lane >> 4;
    int tile = blockIdx.x * 64;

    // ===== GEMM phase =====
    bf16x8 ah[4][4], al[4][4];
#pragma unroll
    for (int m = 0; m < 4; ++m) {
        int node = tile + m * 16 + nl;
        if (node >= NN) node = NN - 1;
        const short* ph = zh + (size_t)node * HD + kg * 8;
        const short* pl = zl + (size_t)node * HD + kg * 8;
#pragma unroll
        for (int ks = 0; ks < 4; ++ks) {
            ah[m][ks] = *(const bf16x8*)(ph + ks * 32);
            al[m][ks] = *(const bf16x8*)(pl + ks * 32);
        }
    }

    f32x4 acc[2][4];
#pragma unroll
    for (int c = 0; c < 2; ++c) {
        int ct = wave * 2 + c;
        bf16x8 wh[4], wl[4];
#pragma unroll
        for (int ks = 0; ks < 4; ++ks) {
            wh[ks] = *(const bf16x8*)(Wh + (ct * 4 + ks) * 512 + lane * 8);
            wl[ks] = *(const bf16x8*)(Wl + (ct * 4 + ks) * 512 + lane * 8);
        }
#pragma unroll
        for (int m = 0; m < 4; ++m) acc[c][m] = (f32x4){0.f, 0.f, 0.f, 0.f};
#pragma unroll
        for (int ks = 0; ks < 4; ++ks)
#pragma unroll
            for (int m = 0; m < 4; ++m) {
                acc[c][m] = __builtin_amdgcn_mfma_f32_16x16x32_bf16(wh[ks], ah[m][ks], acc[c][m], 0, 0, 0);
                acc[c][m] = __builtin_amdgcn_mfma_f32_16x16x32_bf16(wh[ks], al[m][ks], acc[c][m], 0, 0, 0);
                acc[c][m] = __builtin_amdgcn_mfma_f32_16x16x32_bf16(wl[ks], ah[m][ks], acc[c][m], 0, 0, 0);
            }
    }
#pragma unroll
    for (int c = 0; c < 2; ++c)
#pragma unroll
        for (int m = 0; m < 4; ++m)
#pragma unroll
            for (int r = 0; r < 4; ++r) acc[c][m][r] = fmaxf(acc[c][m][r], 0.f);

    float scale[4] = {1.f, 1.f, 1.f, 1.f};
    if (do_norm) {
        float ss[4];
#pragma unroll
        for (int m = 0; m < 4; ++m) {
            float s = 0.f;
#pragma unroll
            for (int c = 0; c < 2; ++c)
#pragma unroll
                for (int r = 0; r < 4; ++r) s = fmaf(acc[c][m][r], acc[c][m][r], s);
            s += __shfl_xor(s, 16, 64);
            s += __shfl_xor(s, 32, 64);
            ss[m] = s;
        }
        if (kg == 0) {
#pragma unroll
            for (int m = 0; m < 4; ++m) redss[wave][m * 16 + nl] = ss[m];
        }
        __syncthreads();
#pragma unroll
        for (int m = 0; m < 4; ++m) {
            int r = m * 16 + nl;
            float tot = redss[0][r] + redss[1][r] + redss[2][r] + redss[3][r];
            scale[m] = 1.f / fmaxf(sqrtf(tot), 1e-12f);
        }
    }

    // x-tile to LDS (bf16, swizzled, stride 256B) + fp16 global
#pragma unroll
    for (int c = 0; c < 2; ++c) {
        int ct = wave * 2 + c;
#pragma unroll
        for (int m = 0; m < 4; ++m) {
            float4 o;
            o.x = acc[c][m][0] * scale[m];
            o.y = acc[c][m][1] * scale[m];
            o.z = acc[c][m][2] * scale[m];
            o.w = acc[c][m][3] * scale[m];
            int r = m * 16 + nl;
            short4 hs;
            hs.x = f2bf(o.x);
            hs.y = f2bf(o.y);
            hs.z = f2bf(o.z);
            hs.w = f2bf(o.w);
            int byte = (r * 256 + ct * 32 + kg * 8) ^ ((r & 7) << 4);
            *(short4*)(Xt + byte) = hs;
            int node = tile + r;
            if (write_x && node < NN) {
                half4v hf;
                hf[0] = (_Float16)o.x;
                hf[1] = (_Float16)o.y;
                hf[2] = (_Float16)o.z;
                hf[3] = (_Float16)o.w;
                *(half4v*)(xfout + (size_t)node * HD + ct * 16 + kg * 4) = hf;
            }
        }
    }
    __syncthreads();

    // ===== MLP phase =====
    bf16x8 a1[4][4];
#pragma unroll
    for (int m = 0; m < 4; ++m) {
        int r = m * 16 + nl;
#pragma unroll
        for (int ks = 0; ks < 4; ++ks) {
            int byte = (r * 256 + ks * 64 + kg * 16) ^ ((r & 7) << 4);
            a1[m][ks] = *(const bf16x8*)(Xt + byte);
        }
    }
    __syncthreads();  // all A1 reads done before H1s overwrites the union

#pragma unroll
    for (int c = 0; c < 4; ++c) {
        int ct = wave * 4 + c;
        bf16x8 w[4];
#pragma unroll
        for (int ks = 0; ks < 4; ++ks)
            w[ks] = *(const bf16x8*)(W1p + (ct * 4 + ks) * 512 + lane * 8);
        f32x4 a[4];
#pragma unroll
        for (int m = 0; m < 4; ++m) a[m] = (f32x4){0.f, 0.f, 0.f, 0.f};
#pragma unroll
        for (int ks = 0; ks < 4; ++ks)
#pragma unroll
            for (int m = 0; m < 4; ++m)
                a[m] = __builtin_amdgcn_mfma_f32_16x16x32_bf16(w[ks], a1[m][ks], a[m], 0, 0, 0);
        float4 b1v = *(const float4*)(L1b + ct * 16 + kg * 4);
#pragma unroll
        for (int m = 0; m < 4; ++m) {
            short4 hs;
            hs.x = f2bf(fmaxf(a[m][0] + b1v.x, 0.f));
            hs.y = f2bf(fmaxf(a[m][1] + b1v.y, 0.f));
            hs.z = f2bf(fmaxf(a[m][2] + b1v.z, 0.f));
            hs.w = f2bf(fmaxf(a[m][3] + b1v.w, 0.f));
            int r = m * 16 + nl;
            int byte = (r * 512 + ct * 32 + kg * 8) ^ ((r & 7) << 4);
            *(short4*)(H1s + byte) = hs;
        }
    }
    __syncthreads();

    bf16x8 a2[4][8];
#pragma unroll
    for (int m = 0; m < 4; ++m) {
        int r = m * 16 + nl;
#pragma unroll
        for (int ks = 0; ks < 8; ++ks) {
            int byte = (r * 512 + ks * 64 + kg * 16) ^ ((r & 7) << 4);
            a2[m][ks] = *(const bf16x8*)(H1s + byte);
        }
    }

    float t[4] = {0.f, 0.f, 0.f, 0.f};
#pragma unroll
    for (int c = 0; c < 4; ++c) {
        int ct = wave * 4 + c;
        bf16x8 w[8];
#pragma unroll
        for (int ks = 0; ks < 8; ++ks)
            w[ks] = *(const bf16x8*)(W2p + (ct * 8 + ks) * 512 + lane * 8);
        f32x4 a[4];
#pragma unroll
        for (int m = 0; m < 4; ++m) a[m] = (f32x4){0.f, 0.f, 0.f, 0.f};
#pragma unroll
        for (int ks = 0; ks < 8; ++ks)
#pragma unroll
            for (int m = 0; m < 4; ++m)
                a[m] = __builtin_amdgcn_mfma_f32_16x16x32_bf16(w[ks], a2[m][ks], a[m], 0, 0, 0);
        float4 b2v = *(const float4*)(L2b + ct * 16 + kg * 4);
        float4 w3v = *(const float4*)(L3w + ct * 16 + kg * 4);
#pragma unroll
        for (int m = 0; m < 4; ++m) {
            t[m] = fmaf(fmaxf(a[m][0] + b2v.x, 0.f), w3v.x, t[m]);
            t[m] = fmaf(fmaxf(a[m][1] + b2v.y, 0.f), w3v.y, t[m]);
            t[m] = fmaf(fmaxf(a[m][2] + b2v.z, 0.f), w3v.z, t[m]);
            t[m] = fmaf(fmaxf(a[m][3] + b2v.w, 0.f), w3v.w, t[m]);
        }
    }
#pragma unroll
    for (int m = 0; m < 4; ++m) {
        t[m] += __shfl_xor(t[m], 16, 64);
        t[m] += __shfl_xor(t[m], 32, 64);
    }
    if (kg == 0) {
#pragma unroll
        for (int m = 0; m < 4; ++m) red[wave][m * 16 + nl] = t[m];
    }
    __syncthreads();
    if (tid < 64) {
        int g = tile + tid;
        if (g < NN) {
            float s = red[0][tid] + red[1][tid] + red[2][tid] + red[3][tid];
            score[g] += s + L3b[0];
        }
    }
}

// ---------------- standalone MLP (layer-1 path), score = (first write) ----------------
__global__ __launch_bounds__(256, 2) void mlp_mfma_kernel(
    const unsigned short* __restrict__ xh, const short* __restrict__ W1p,
    const float* __restrict__ L1b, const short* __restrict__ W2p,
    const float* __restrict__ L2b, const float* __restrict__ L3w,
    const float* __restrict__ L3b, float* __restrict__ score) {
    __shared__ __align__(16) char H1s[32768];
    __shared__ float red[4][64];
    int tid = threadIdx.x;
    int wave = tid >> 6, lane = tid & 63;
    int nl = lane & 15, kg = lane >> 4;
    int tile = blockIdx.x * 64;

    bf16x8 a1[4][4];
#pragma unroll
    for (int m = 0; m < 4; ++m) {
        int node = tile + m * 16 + nl;
        if (node >= NN) node = NN - 1;
        const short* xr = (const short*)xh + (size_t)node * HD + kg * 8;
#pragma unroll
        for (int ks = 0; ks < 4; ++ks) a1[m][ks] = *(const bf16x8*)(xr + ks * 32);
    }

#pragma unroll
    for (int c = 0; c < 4; ++c) {
        int ct = wave * 4 + c;
        bf16x8 w[4];
#pragma unroll
        for (int ks = 0; ks < 4; ++ks)
            w[ks] = *(const bf16x8*)(W1p + (ct * 4 + ks) * 512 + lane * 8);
        f32x4 a[4];
#pragma unroll
        for (int m = 0; m < 4; ++m) a[m] = (f32x4){0.f, 0.f, 0.f, 0.f};
#pragma unroll
        for (int ks = 0; ks < 4; ++ks)
#pragma unroll
            for (int m = 0; m < 4; ++m)
                a[m] = __builtin_amdgcn_mfma_f32_16x16x32_bf16(w[ks], a1[m][ks], a[m], 0, 0, 0);
        float4 b1v = *(const float4*)(L1b + ct * 16 + kg * 4);
#pragma unroll
        for (int m = 0; m < 4; ++m) {
            short4 hs;
            hs.x = f2bf(fmaxf(a[m][0] + b1v.x, 0.f));
            hs.y = f2bf(fmaxf(a[m][1] + b1v.y, 0.f));
            hs.z = f2bf(fmaxf(a[m][2] + b1v.z, 0.f));
            hs.w = f2bf(fmaxf(a[m][3] + b1v.w, 0.f));
            int r = m * 16 + nl;
            int byte = (r * 512 + ct * 32 + kg * 8) ^ ((r & 7) << 4);
            *(short4*)(H1s + byte) = hs;
        }
    }
    __syncthreads();

    bf16x8 a2[4][8];
#pragma unroll
    for (int m = 0; m < 4; ++m) {
        int r = m * 16 + nl;
#pragma unroll
        for (int ks = 0; ks < 8; ++ks) {
            int byte = (r * 512 + ks * 64 + kg * 16) ^ ((r & 7) << 4);
            a2[m][ks] = *(const bf16x8*)(H1s + byte);
        }
    }

    float t[4] = {0.f, 0.f, 0.f, 0.f};
#pragma unroll
    for (int c = 0; c < 4; ++c) {
        int ct = wave * 4 + c;
        bf16x8 w[8];
#pragma unroll
        for (int ks = 0; ks < 8; ++ks)
            w[ks] = *(const bf16x8*)(W2p + (ct * 8 + ks) * 512 + lane * 8);
        f32x4 a[4];
#pragma unroll
        for (int m = 0; m < 4; ++m) a[m] = (f32x4){0.f, 0.f, 0.f, 0.f};
#pragma unroll
        for (int ks = 0; ks < 8; ++ks)
#pragma unroll
            for (int m = 0; m < 4; ++m)
                a[m] = __builtin_amdgcn_mfma_f32_16x16x32_bf16(w[ks], a2[m][ks], a[m], 0, 0, 0);
        float4 b2v = *(const float4*)(L2b + ct * 16 + kg * 4);
        float4 w3v = *(const float4*)(L3w + ct * 16 + kg * 4);
#pragma unroll
        for (int m = 0; m < 4; ++m) {
            t[m] = fmaf(fmaxf(a[m][0] + b2v.x, 0.f), w3v.x, t[m]);
            t[m] = fmaf(fmaxf(a[m][1] + b2v.y, 0.f), w3v.y, t[m]);
            t[m] = fmaf(fmaxf(a[m][2] + b2v.z, 0.f), w3v.z, t[m]);
            t[m] = fmaf(fmaxf(a[m][3] + b2v.w, 0.f), w3v.w, t[m]);
        }
    }
#pragma unroll
    for (int m = 0; m < 4; ++m) {
        t[m] += __shfl_xor(t[m], 16, 64);
        t[m] += __shfl_xor(t[m], 32, 64);
    }
    if (kg == 0) {
#pragma unroll
        for (int m = 0; m < 4; ++m) red[wave][m * 16 + nl] = t[m];
    }
    __syncthreads();
    if (tid < 64) {
        int g = tile + tid;
        if (g < NN) {
            float s = red[0][tid] + red[1][tid] + red[2][tid] + red[3][tid];
            score[g] = s + L3b[0];  // first MLP writes (no memset needed)
        }
    }
}

__global__ void final_kernel(const float* __restrict__ s1, const float* __restrict__ s2,
                             float* __restrict__ out) {
    int i = blockIdx.x * blockDim.x + threadIdx.x;
    if (i < NN) out[i] = s1[i] * s2[i];
}

extern "C" void kernel_launch(void* const* d_in, const int* in_sizes, int n_in,
                              void* d_out, int out_size, void* d_ws, size_t ws_size,
                              hipStream_t stream) {
    const int* row1 = (const int*)d_in[0];
    const int* col1 = (const int*)d_in[1];
    const float* val1 = (const float*)d_in[2];
    const int* row2 = (const int*)d_in[3];
    const int* col2 = (const int*)d_in[4];
    const float* val2 = (const float*)d_in[5];
    const float* W0 = (const float*)d_in[6];
    const float* Wg[4] = {(const float*)d_in[7], (const float*)d_in[8], (const float*)d_in[9],
                          (const float*)d_in[10]};
    const float* L1w = (const float*)d_in[11];
    const float* L1b = (const float*)d_in[12];
    const float* L2w = (const float*)d_in[13];
    const float* L2b = (const float*)d_in[14];
    const float* L3w = (const float*)d_in[15];
    const float* L3b = (const float*)d_in[16];
    float* out = (float*)d_out;

    char* ws = (char*)d_ws;
    size_t off = 0;
    auto alloc = [&](size_t bytes) {
        void* p = ws + off;
        off = (off + bytes + 255) & ~(size_t)255;
        return p;
    };
    int* rp1 = (int*)alloc((NN + 1) * 4);
    int* cols1 = (int*)alloc(EE * 4);
    float* vals1 = (float*)alloc(EE * 4);
    int* rp2 = (int*)alloc((NN + 1) * 4);
    int* cols2 = (int*)alloc(EE * 4);
    float* vals2 = (float*)alloc(EE * 4);
    int* cntcur = (int*)alloc(4 * NN * 4);  // cnt1,cnt2,cur1,cur2
    float* s1 = (float*)alloc(NN * 4);
    float* s2 = (float*)alloc(NN * 4);
    unsigned short* xh = (unsigned short*)alloc((size_t)NN * HD * 2);
    _Float16* xf = (_Float16*)alloc((size_t)NN * HD * 2);
    _Float16* w0h = (_Float16*)alloc((size_t)NN * HD * 2);
    short* zh = (short*)alloc((size_t)NN * HD * 2);
    short* zl = (short*)alloc((size_t)NN * HD * 2);
    short* W1p = (short*)alloc(16 * 4 * 512 * 2);
    short* W2p = (short*)alloc(16 * 8 * 512 * 2);
    short* Wgh[4];
    short* Wgl[4];
    for (int l = 0; l < 4; ++l) {
        Wgh[l] = (short*)alloc(8 * 4 * 512 * 2);
        Wgl[l] = (short*)alloc(8 * 4 * 512 * 2);
    }
    int* cnt = cntcur;
    int* cur = cntcur + 2 * NN;

    // ---- prep ----
    pack_all_kernel<<<112, 256, 0, stream>>>(L1w, W1p, L2w, W2p, Wg[0], Wg[1], Wg[2], Wg[3],
                                             Wgh[0], Wgl[0], Wgh[1], Wgl[1], Wgh[2], Wgl[2],
                                             Wgh[3], Wgl[3]);
    cvt_w0_kernel<<<(NN * HD / 4 + 255) / 256, 256, 0, stream>>>(W0, w0h);
    hipMemsetAsync(cntcur, 0, 4 * NN * 4, stream);
    hist2_kernel<<<(2 * EE + 255) / 256, 256, 0, stream>>>(row1, row2, cnt);
    scan2_kernel<<<2, 1024, 0, stream>>>(cnt, rp1, rp2);
    scatter2_kernel<<<(2 * EE + 255) / 256, 256, 0, stream>>>(
        row1, col1, val1, row2, col2, val2, rp1, rp2, cur, cols1, vals1, cols2, vals2);

    int spmm_grid = (NN * 32 + 255) / 256;
    int tile_grid = (NN + 63) / 64;
    auto branch = [&](const int* rp, const int* cols, const float* vals, float* sc) {
        spmm_norm_kernel<<<spmm_grid, 256, 0, stream>>>(rp, cols, vals, w0h, xf, xh);
        mlp_mfma_kernel<<<tile_grid, 256, 0, stream>>>(xh, W1p, L1b, W2p, L2b, L3w, L3b, sc);
        for (int l = 0; l < 4; ++l) {
            spmm_raw_kernel<<<spmm_grid, 256, 0, stream>>>(rp, cols, vals, xf, zh, zl);
            gemm_mlp_kernel<<<tile_grid, 256, 0, stream>>>(zh, zl, Wgh[l], Wgl[l], W1p, L1b,
                                                           W2p, L2b, L3w, L3b, xf, sc,
                                                           l < 3 ? 1 : 0, l < 3 ? 1 : 0);
        }
    };
    branch(rp1, cols1, vals1, s1);
    branch(rp2, cols2, vals2, s2);

    final_kernel<<<(NN + 255) / 256, 256, 0, stream>>>(s1, s2, out);
}

// Round 9
// 662.761 us; speedup vs baseline: 1.0957x; 1.0957x over previous
//
#include <hip/hip_runtime.h>

#define NN 50000
#define EE 250000
#define HD 128

typedef __attribute__((ext_vector_type(8))) short bf16x8;
typedef __attribute__((ext_vector_type(4))) float f32x4;
typedef _Float16 half8v __attribute__((ext_vector_type(8)));

__device__ inline short f2bf(float f) {
    unsigned u = __builtin_bit_cast(unsigned, f);
    unsigned r = u + 0x7fffu + ((u >> 16) & 1u);
    return (short)(r >> 16);
}
__device__ inline float bf2f(short h) {
    unsigned u = ((unsigned)(unsigned short)h) << 16;
    return __builtin_bit_cast(float, u);
}

// ---------------- CSR build (both graphs in one launch) ----------------
__global__ void hist2_kernel(const int* __restrict__ row1, const int* __restrict__ row2,
                             int* __restrict__ cnt) {
    int t = blockIdx.x * blockDim.x + threadIdx.x;
    if (t >= 2 * EE) return;
    int g = t >= EE;
    int e = t - g * EE;
    const int* row = g ? row2 : row1;
    atomicAdd(&cnt[g * NN + row[e]], 1);
}

__global__ __launch_bounds__(1024) void scan2_kernel(const int* __restrict__ cnt_all,
                                                     int* __restrict__ rp1,
                                                     int* __restrict__ rp2) {
    __shared__ int s[1024];
    const int* cnt = cnt_all + blockIdx.x * NN;
    int* rp = blockIdx.x ? rp2 : rp1;
    int tid = threadIdx.x;
    int c0 = 0;
    for (int base = 0; base < NN; base += 8192) {
        int v[8];
        int sum = 0;
        int i0 = base + tid * 8;
#pragma unroll
        for (int j = 0; j < 8; ++j) {
            int i = i0 + j;
            v[j] = (i < NN) ? cnt[i] : 0;
            sum += v[j];
        }
        s[tid] = sum;
        __syncthreads();
        for (int off = 1; off < 1024; off <<= 1) {
            int t2 = (tid >= off) ? s[tid - off] : 0;
            __syncthreads();
            s[tid] += t2;
            __syncthreads();
        }
        int excl = c0 + s[tid] - sum;
#pragma unroll
        for (int j = 0; j < 8; ++j) {
            int i = i0 + j;
            if (i < NN) rp[i] = excl;
            excl += v[j];
        }
        int tot = s[1023];
        __syncthreads();
        c0 += tot;
    }
    if (tid == 0) rp[NN] = c0;
}

__global__ void scatter2_kernel(const int* __restrict__ row1, const int* __restrict__ col1,
                                const float* __restrict__ val1, const int* __restrict__ row2,
                                const int* __restrict__ col2, const float* __restrict__ val2,
                                const int* __restrict__ rp1, const int* __restrict__ rp2,
                                int* __restrict__ cur, int* __restrict__ cols1_s,
                                float* __restrict__ vals1_s, int* __restrict__ cols2_s,
                                float* __restrict__ vals2_s) {
    int t = blockIdx.x * blockDim.x + threadIdx.x;
    if (t >= 2 * EE) return;
    int g = t >= EE;
    int e = t - g * EE;
    const int* row = g ? row2 : row1;
    const int* col = g ? col2 : col1;
    const float* val = g ? val2 : val1;
    const int* rp = g ? rp2 : rp1;
    int* cols_s = g ? cols2_s : cols1_s;
    float* vals_s = g ? vals2_s : vals1_s;
    int r = row[e];
    int p = atomicAdd(&cur[g * NN + r], 1);
    int d = rp[r] + p;
    cols_s[d] = col[e];
    vals_s[d] = val[e];
}

// ---------------- weight pack (all 10 sections in one launch) ----------------
__device__ inline void pack_one(const float* __restrict__ in, short* __restrict__ out,
                                int NCOL, int NKS, int lo, int t) {
    int lane = t & 63, f = t >> 6;
    int ks = f % NKS, ct = f / NKS;
    int nl = lane & 15, kg = lane >> 4;
    int c = ct * 16 + nl;
    bf16x8 o;
#pragma unroll
    for (int j = 0; j < 8; ++j) {
        int k = ks * 32 + kg * 8 + j;
        float v = in[k * NCOL + c];
        short h = f2bf(v);
        o[j] = lo ? f2bf(v - bf2f(h)) : h;
    }
    *(bf16x8*)(out + f * 512 + lane * 8) = o;
}

__global__ void pack_all_kernel(const float* __restrict__ L1w, short* __restrict__ W1p,
                                const float* __restrict__ L2w, short* __restrict__ W2p,
                                const float* __restrict__ Wg0, const float* __restrict__ Wg1,
                                const float* __restrict__ Wg2, const float* __restrict__ Wg3,
                                short* __restrict__ Wh0, short* __restrict__ Wl0,
                                short* __restrict__ Wh1, short* __restrict__ Wl1,
                                short* __restrict__ Wh2, short* __restrict__ Wl2,
                                short* __restrict__ Wh3, short* __restrict__ Wl3) {
    int t = blockIdx.x * 256 + threadIdx.x;
    if (t < 4096) {
        pack_one(L1w, W1p, 256, 4, 0, t);
    } else if (t < 12288) {
        pack_one(L2w, W2p, 256, 8, 0, t - 4096);
    } else if (t < 28672) {
        int u = t - 12288;
        int l = u >> 12;
        int lo = (u >> 11) & 1;
        int tt = u & 2047;
        const float* in = l == 0 ? Wg0 : l == 1 ? Wg1 : l == 2 ? Wg2 : Wg3;
        short* out = l == 0 ? (lo ? Wl0 : Wh0)
                   : l == 1 ? (lo ? Wl1 : Wh1)
                   : l == 2 ? (lo ? Wl2 : Wh2)
                            : (lo ? Wl3 : Wh3);
        pack_one(in, out, 128, 4, lo, tt);
    }
}

__global__ void cvt_w0_kernel(const float* __restrict__ in, _Float16* __restrict__ out) {
    int t = blockIdx.x * 256 + threadIdx.x;
    int i = t * 8;
    if (i >= NN * HD) return;
    float4 a = *(const float4*)(in + i);
    float4 b = *(const float4*)(in + i + 4);
    half8v h;
    h[0] = (_Float16)a.x; h[1] = (_Float16)a.y; h[2] = (_Float16)a.z; h[3] = (_Float16)a.w;
    h[4] = (_Float16)b.x; h[5] = (_Float16)b.y; h[6] = (_Float16)b.z; h[7] = (_Float16)b.w;
    *(half8v*)(out + i) = h;
}

// ---------------- SpMM layer-1 (both graphs): l2norm(relu(A @ W0h)) ----------------
// 4 rows/wave, 16 lanes x fp16x8 (16B/lane); edge loop unrolled x8 branch-free.
__global__ __launch_bounds__(256) void spmm_norm_kernel(
    const int* __restrict__ rp1, const int* __restrict__ cols1, const float* __restrict__ vals1,
    const int* __restrict__ rp2, const int* __restrict__ cols2, const float* __restrict__ vals2,
    const _Float16* __restrict__ xin, _Float16* __restrict__ xf1, unsigned short* __restrict__ xh1,
    _Float16* __restrict__ xf2, unsigned short* __restrict__ xh2) {
    int rr = (blockIdx.x * 256 + threadIdx.x) >> 4;
    int ln = threadIdx.x & 15;
    if (rr >= 2 * NN) return;
    int g = rr >= NN;
    int r = rr - g * NN;
    const int* rp = g ? rp2 : rp1;
    const int* cols = g ? cols2 : cols1;
    const float* vals = g ? vals2 : vals1;
    _Float16* xf = g ? xf2 : xf1;
    unsigned short* xh = g ? xh2 : xh1;
    int beg = rp[r], end = rp[r + 1];
    float acc[8] = {};
    for (int e = beg; e < end; e += 8) {
#pragma unroll
        for (int i = 0; i < 8; ++i) {
            int ei = e + i;
            int idx = ei < end ? ei : end - 1;
            int c = cols[idx];
            float v = ei < end ? vals[idx] : 0.f;
            half8v xr = *(const half8v*)(xin + (size_t)c * HD + ln * 8);
#pragma unroll
            for (int j = 0; j < 8; ++j) acc[j] = fmaf(v, (float)xr[j], acc[j]);
        }
    }
    float ss = 0.f;
#pragma unroll
    for (int j = 0; j < 8; ++j) {
        acc[j] = fmaxf(acc[j], 0.f);
        ss = fmaf(acc[j], acc[j], ss);
    }
#pragma unroll
    for (int off = 1; off < 16; off <<= 1) ss += __shfl_xor(ss, off, 64);
    float sc = 1.f / fmaxf(sqrtf(ss), 1e-12f);
    half8v hf;
    bf16x8 hs;
#pragma unroll
    for (int j = 0; j < 8; ++j) {
        float o = acc[j] * sc;
        hf[j] = (_Float16)o;
        hs[j] = f2bf(o);
    }
    *(half8v*)(xf + (size_t)r * HD + ln * 8) = hf;
    *(bf16x8*)((short*)xh + (size_t)r * HD + ln * 8) = hs;
}

// ---------------- SpMM raw (both graphs): z = A @ xf16, split bf16 ----------------
__global__ __launch_bounds__(256) void spmm_raw_kernel(
    const int* __restrict__ rp1, const int* __restrict__ cols1, const float* __restrict__ vals1,
    const int* __restrict__ rp2, const int* __restrict__ cols2, const float* __restrict__ vals2,
    const _Float16* __restrict__ xf1, const _Float16* __restrict__ xf2,
    short* __restrict__ zh1, short* __restrict__ zl1, short* __restrict__ zh2,
    short* __restrict__ zl2) {
    int rr = (blockIdx.x * 256 + threadIdx.x) >> 4;
    int ln = threadIdx.x & 15;
    if (rr >= 2 * NN) return;
    int g = rr >= NN;
    int r = rr - g * NN;
    const int* rp = g ? rp2 : rp1;
    const int* cols = g ? cols2 : cols1;
    const float* vals = g ? vals2 : vals1;
    const _Float16* xin = g ? xf2 : xf1;
    short* zh = g ? zh2 : zh1;
    short* zl = g ? zl2 : zl1;
    int beg = rp[r], end = rp[r + 1];
    float acc[8] = {};
    for (int e = beg; e < end; e += 8) {
#pragma unroll
        for (int i = 0; i < 8; ++i) {
            int ei = e + i;
            int idx = ei < end ? ei : end - 1;
            int c = cols[idx];
            float v = ei < end ? vals[idx] : 0.f;
            half8v xr = *(const half8v*)(xin + (size_t)c * HD + ln * 8);
#pragma unroll
            for (int j = 0; j < 8; ++j) acc[j] = fmaf(v, (float)xr[j], acc[j]);
        }
    }
    bf16x8 hh, hl;
#pragma unroll
    for (int j = 0; j < 8; ++j) {
        short h = f2bf(acc[j]);
        hh[j] = h;
        hl[j] = f2bf(acc[j] - bf2f(h));
    }
    *(bf16x8*)(zh + (size_t)r * HD + ln * 8) = hh;
    *(bf16x8*)(zl + (size_t)r * HD + ln * 8) = hl;
}

// ---------------- fused GEMM + MLP (both graphs in one grid) ----------------
__global__ __launch_bounds__(256, 2) void gemm_mlp_kernel(
    const short* __restrict__ zh1, const short* __restrict__ zl1,
    const short* __restrict__ zh2, const short* __restrict__ zl2,
    const short* __restrict__ Wh, const short* __restrict__ Wl,
    const short* __restrict__ W1p, const float* __restrict__ L1b,
    const short* __restrict__ W2p, const float* __restrict__ L2b,
    const float* __restrict__ L3w, const float* __restrict__ L3b,
    _Float16* __restrict__ xf1, _Float16* __restrict__ xf2, float* __restrict__ s1,
    float* __restrict__ s2, int ngrid, int do_norm, int write_x) {
    __shared__ __align__(16) char U[32768];  // Xt (16KB) then reused as H1s (32KB)
    __shared__ float redss[4][64];
    __shared__ float red[4][64];
    char* Xt = U;
    char* H1s = U;
    int tid = threadIdx.x;
    int wave = tid >> 6, lane = tid & 63;
    int nl = lane & 15, kg = lane >> 4;
    int g = blockIdx.x >= ngrid;
    int tile = (blockIdx.x - g * ngrid) * 64;
    const short* zh = g ? zh2 : zh1;
    const short* zl = g ? zl2 : zl1;
    _Float16* xfout = g ? xf2 : xf1;
    float* score = g ? s2 : s1;

    // ===== GEMM phase =====
    bf16x8 ah[4][4], al[4][4];
#pragma unroll
    for (int m = 0; m < 4; ++m) {
        int node = tile + m * 16 + nl;
        if (node >= NN) node = NN - 1;
        const short* ph = zh + (size_t)node * HD + kg * 8;
        const short* pl = zl + (size_t)node * HD + kg * 8;
#pragma unroll
        for (int ks = 0; ks < 4; ++ks) {
            ah[m][ks] = *(const bf16x8*)(ph + ks * 32);
            al[m][ks] = *(const bf16x8*)(pl + ks * 32);
        }
    }

    f32x4 acc[2][4];
#pragma unroll
    for (int c = 0; c < 2; ++c) {
        int ct = wave * 2 + c;
        bf16x8 wh[4], wl[4];
#pragma unroll
        for (int ks = 0; ks < 4; ++ks) {
            wh[ks] = *(const bf16x8*)(Wh + (ct * 4 + ks) * 512 + lane * 8);
            wl[ks] = *(const bf16x8*)(Wl + (ct * 4 + ks) * 512 + lane * 8);
        }
#pragma unroll
        for (int m = 0; m < 4; ++m) acc[c][m] = (f32x4){0.f, 0.f, 0.f, 0.f};
#pragma unroll
        for (int ks = 0; ks < 4; ++ks)
#pragma unroll
            for (int m = 0; m < 4; ++m) {
                acc[c][m] = __builtin_amdgcn_mfma_f32_16x16x32_bf16(wh[ks], ah[m][ks], acc[c][m], 0, 0, 0);
                acc[c][m] = __builtin_amdgcn_mfma_f32_16x16x32_bf16(wh[ks], al[m][ks], acc[c][m], 0, 0, 0);
                acc[c][m] = __builtin_amdgcn_mfma_f32_16x16x32_bf16(wl[ks], ah[m][ks], acc[c][m], 0, 0, 0);
            }
    }
#pragma unroll
    for (int c = 0; c < 2; ++c)
#pragma unroll
        for (int m = 0; m < 4; ++m)
#pragma unroll
            for (int r = 0; r < 4; ++r) acc[c][m][r] = fmaxf(acc[c][m][r], 0.f);

    float scale[4] = {1.f, 1.f, 1.f, 1.f};
    if (do_norm) {
        float ss[4];
#pragma unroll
        for (int m = 0; m < 4; ++m) {
            float s = 0.f;
#pragma unroll
            for (int c = 0; c < 2; ++c)
#pragma unroll
                for (int r = 0; r < 4; ++r) s = fmaf(acc[c][m][r], acc[c][m][r], s);
            s += __shfl_xor(s, 16, 64);
            s += __shfl_xor(s, 32, 64);
            ss[m] = s;
        }
        if (kg == 0) {
#pragma unroll
            for (int m = 0; m < 4; ++m) redss[wave][m * 16 + nl] = ss[m];
        }
        __syncthreads();
#pragma unroll
        for (int m = 0; m < 4; ++m) {
            int r = m * 16 + nl;
            float tot = redss[0][r] + redss[1][r] + redss[2][r] + redss[3][r];
            scale[m] = 1.f / fmaxf(sqrtf(tot), 1e-12f);
        }
    }

    // x-tile to LDS (bf16, swizzled, stride 256B) + fp16 global
#pragma unroll
    for (int c = 0; c < 2; ++c) {
        int ct = wave * 2 + c;
#pragma unroll
        for (int m = 0; m < 4; ++m) {
            float4 o;
            o.x = acc[c][m][0] * scale[m];
            o.y = acc[c][m][1] * scale[m];
            o.z = acc[c][m][2] * scale[m];
            o.w = acc[c][m][3] * scale[m];
            int r = m * 16 + nl;
            short4 hs;
            hs.x = f2bf(o.x);
            hs.y = f2bf(o.y);
            hs.z = f2bf(o.z);
            hs.w = f2bf(o.w);
            int byte = (r * 256 + ct * 32 + kg * 8) ^ ((r & 7) << 4);
            *(short4*)(Xt + byte) = hs;
            int node = tile + r;
            if (write_x && node < NN) {
                _Float16 hf4[4];
                hf4[0] = (_Float16)o.x;
                hf4[1] = (_Float16)o.y;
                hf4[2] = (_Float16)o.z;
                hf4[3] = (_Float16)o.w;
                *(float2*)(xfout + (size_t)node * HD + ct * 16 + kg * 4) =
                    *(float2*)hf4;
            }
        }
    }
    __syncthreads();

    // ===== MLP phase =====
    bf16x8 a1[4][4];
#pragma unroll
    for (int m = 0; m < 4; ++m) {
        int r = m * 16 + nl;
#pragma unroll
        for (int ks = 0; ks < 4; ++ks) {
            int byte = (r * 256 + ks * 64 + kg * 16) ^ ((r & 7) << 4);
            a1[m][ks] = *(const bf16x8*)(Xt + byte);
        }
    }
    __syncthreads();  // all A1 reads done before H1s overwrites the union

#pragma unroll
    for (int c = 0; c < 4; ++c) {
        int ct = wave * 4 + c;
        bf16x8 w[4];
#pragma unroll
        for (int ks = 0; ks < 4; ++ks)
            w[ks] = *(const bf16x8*)(W1p + (ct * 4 + ks) * 512 + lane * 8);
        f32x4 a[4];
#pragma unroll
        for (int m = 0; m < 4; ++m) a[m] = (f32x4){0.f, 0.f, 0.f, 0.f};
#pragma unroll
        for (int ks = 0; ks < 4; ++ks)
#pragma unroll
            for (int m = 0; m < 4; ++m)
                a[m] = __builtin_amdgcn_mfma_f32_16x16x32_bf16(w[ks], a1[m][ks], a[m], 0, 0, 0);
        float4 b1v = *(const float4*)(L1b + ct * 16 + kg * 4);
#pragma unroll
        for (int m = 0; m < 4; ++m) {
            short4 hs;
            hs.x = f2bf(fmaxf(a[m][0] + b1v.x, 0.f));
            hs.y = f2bf(fmaxf(a[m][1] + b1v.y, 0.f));
            hs.z = f2bf(fmaxf(a[m][2] + b1v.z, 0.f));
            hs.w = f2bf(fmaxf(a[m][3] + b1v.w, 0.f));
            int r = m * 16 + nl;
            int byte = (r * 512 + ct * 32 + kg * 8) ^ ((r & 7) << 4);
            *(short4*)(H1s + byte) = hs;
        }
    }
    __syncthreads();

    bf16x8 a2[4][8];
#pragma unroll
    for (int m = 0; m < 4; ++m) {
        int r = m * 16 + nl;
#pragma unroll
        for (int ks = 0; ks < 8; ++ks) {
            int byte = (r * 512 + ks * 64 + kg * 16) ^ ((r & 7) << 4);
            a2[m][ks] = *(const bf16x8*)(H1s + byte);
        }
    }

    float t[4] = {0.f, 0.f, 0.f, 0.f};
#pragma unroll
    for (int c = 0; c < 4; ++c) {
        int ct = wave * 4 + c;
        bf16x8 w[8];
#pragma unroll
        for (int ks = 0; ks < 8; ++ks)
            w[ks] = *(const bf16x8*)(W2p + (ct * 8 + ks) * 512 + lane * 8);
        f32x4 a[4];
#pragma unroll
        for (int m = 0; m < 4; ++m) a[m] = (f32x4){0.f, 0.f, 0.f, 0.f};
#pragma unroll
        for (int ks = 0; ks < 8; ++ks)
#pragma unroll
            for (int m = 0; m < 4; ++m)
                a[m] = __builtin_amdgcn_mfma_f32_16x16x32_bf16(w[ks], a2[m][ks], a[m], 0, 0, 0);
        float4 b2v = *(const float4*)(L2b + ct * 16 + kg * 4);
        float4 w3v = *(const float4*)(L3w + ct * 16 + kg * 4);
#pragma unroll
        for (int m = 0; m < 4; ++m) {
            t[m] = fmaf(fmaxf(a[m][0] + b2v.x, 0.f), w3v.x, t[m]);
            t[m] = fmaf(fmaxf(a[m][1] + b2v.y, 0.f), w3v.y, t[m]);
            t[m] = fmaf(fmaxf(a[m][2] + b2v.z, 0.f), w3v.z, t[m]);
            t[m] = fmaf(fmaxf(a[m][3] + b2v.w, 0.f), w3v.w, t[m]);
        }
    }
#pragma unroll
    for (int m = 0; m < 4; ++m) {
        t[m] += __shfl_xor(t[m], 16, 64);
        t[m] += __shfl_xor(t[m], 32, 64);
    }
    if (kg == 0) {
#pragma unroll
        for (int m = 0; m < 4; ++m) red[wave][m * 16 + nl] = t[m];
    }
    __syncthreads();
    if (tid < 64) {
        int gg = tile + tid;
        if (gg < NN) {
            float s = red[0][tid] + red[1][tid] + red[2][tid] + red[3][tid];
            score[gg] += s + L3b[0];
        }
    }
}

// ---------------- standalone MLP (layer-1 path, both graphs), score = ----------------
__global__ __launch_bounds__(256, 2) void mlp_mfma_kernel(
    const unsigned short* __restrict__ xh1, const unsigned short* __restrict__ xh2,
    const short* __restrict__ W1p, const float* __restrict__ L1b,
    const short* __restrict__ W2p, const float* __restrict__ L2b,
    const float* __restrict__ L3w, const float* __restrict__ L3b, float* __restrict__ s1,
    float* __restrict__ s2, int ngrid) {
    __shared__ __align__(16) char H1s[32768];
    __shared__ float red[4][64];
    int tid = threadIdx.x;
    int wave = tid >> 6, lane = tid & 63;
    int nl = lane & 15, kg = lane >> 4;
    int g = blockIdx.x >= ngrid;
    int tile = (blockIdx.x - g * ngrid) * 64;
    const unsigned short* xh = g ? xh2 : xh1;
    float* score = g ? s2 : s1;

    bf16x8 a1[4][4];
#pragma unroll
    for (int m = 0; m < 4; ++m) {
        int node = tile + m * 16 + nl;
        if (node >= NN) node = NN - 1;
        const short* xr = (const short*)xh + (size_t)node * HD + kg * 8;
#pragma unroll
        for (int ks = 0; ks < 4; ++ks) a1[m][ks] = *(const bf16x8*)(xr + ks * 32);
    }

#pragma unroll
    for (int c = 0; c < 4; ++c) {
        int ct = wave * 4 + c;
        bf16x8 w[4];
#pragma unroll
        for (int ks = 0; ks < 4; ++ks)
            w[ks] = *(const bf16x8*)(W1p + (ct * 4 + ks) * 512 + lane * 8);
        f32x4 a[4];
#pragma unroll
        for (int m = 0; m < 4; ++m) a[m] = (f32x4){0.f, 0.f, 0.f, 0.f};
#pragma unroll
        for (int ks = 0; ks < 4; ++ks)
#pragma unroll
            for (int m = 0; m < 4; ++m)
                a[m] = __builtin_amdgcn_mfma_f32_16x16x32_bf16(w[ks], a1[m][ks], a[m], 0, 0, 0);
        float4 b1v = *(const float4*)(L1b + ct * 16 + kg * 4);
#pragma unroll
        for (int m = 0; m < 4; ++m) {
            short4 hs;
            hs.x = f2bf(fmaxf(a[m][0] + b1v.x, 0.f));
            hs.y = f2bf(fmaxf(a[m][1] + b1v.y, 0.f));
            hs.z = f2bf(fmaxf(a[m][2] + b1v.z, 0.f));
            hs.w = f2bf(fmaxf(a[m][3] + b1v.w, 0.f));
            int r = m * 16 + nl;
            int byte = (r * 512 + ct * 32 + kg * 8) ^ ((r & 7) << 4);
            *(short4*)(H1s + byte) = hs;
        }
    }
    __syncthreads();

    bf16x8 a2[4][8];
#pragma unroll
    for (int m = 0; m < 4; ++m) {
        int r = m * 16 + nl;
#pragma unroll
        for (int ks = 0; ks < 8; ++ks) {
            int byte = (r * 512 + ks * 64 + kg * 16) ^ ((r & 7) << 4);
            a2[m][ks] = *(const bf16x8*)(H1s + byte);
        }
    }

    float t[4] = {0.f, 0.f, 0.f, 0.f};
#pragma unroll
    for (int c = 0; c < 4; ++c) {
        int ct = wave * 4 + c;
        bf16x8 w[8];
#pragma unroll
        for (int ks = 0; ks < 8; ++ks)
            w[ks] = *(const bf16x8*)(W2p + (ct * 8 + ks) * 512 + lane * 8);
        f32x4 a[4];
#pragma unroll
        for (int m = 0; m < 4; ++m) a[m] = (f32x4){0.f, 0.f, 0.f, 0.f};
#pragma unroll
        for (int ks = 0; ks < 8; ++ks)
#pragma unroll
            for (int m = 0; m < 4; ++m)
                a[m] = __builtin_amdgcn_mfma_f32_16x16x32_bf16(w[ks], a2[m][ks], a[m], 0, 0, 0);
        float4 b2v = *(const float4*)(L2b + ct * 16 + kg * 4);
        float4 w3v = *(const float4*)(L3w + ct * 16 + kg * 4);
#pragma unroll
        for (int m = 0; m < 4; ++m) {
            t[m] = fmaf(fmaxf(a[m][0] + b2v.x, 0.f), w3v.x, t[m]);
            t[m] = fmaf(fmaxf(a[m][1] + b2v.y, 0.f), w3v.y, t[m]);
            t[m] = fmaf(fmaxf(a[m][2] + b2v.z, 0.f), w3v.z, t[m]);
            t[m] = fmaf(fmaxf(a[m][3] + b2v.w, 0.f), w3v.w, t[m]);
        }
    }
#pragma unroll
    for (int m = 0; m < 4; ++m) {
        t[m] += __shfl_xor(t[m], 16, 64);
        t[m] += __shfl_xor(t[m], 32, 64);
    }
    if (kg == 0) {
#pragma unroll
        for (int m = 0; m < 4; ++m) red[wave][m * 16 + nl] = t[m];
    }
    __syncthreads();
    if (tid < 64) {
        int gg = tile + tid;
        if (gg < NN) {
            float s = red[0][tid] + red[1][tid] + red[2][tid] + red[3][tid];
            score[gg] = s + L3b[0];  // first MLP writes (no memset needed)
        }
    }
}

__global__ void final_kernel(const float* __restrict__ s1, const float* __restrict__ s2,
                             float* __restrict__ out) {
    int i = blockIdx.x * blockDim.x + threadIdx.x;
    if (i < NN) out[i] = s1[i] * s2[i];
}

extern "C" void kernel_launch(void* const* d_in, const int* in_sizes, int n_in,
                              void* d_out, int out_size, void* d_ws, size_t ws_size,
                              hipStream_t stream) {
    const int* row1 = (const int*)d_in[0];
    const int* col1 = (const int*)d_in[1];
    const float* val1 = (const float*)d_in[2];
    const int* row2 = (const int*)d_in[3];
    const int* col2 = (const int*)d_in[4];
    const float* val2 = (const float*)d_in[5];
    const float* W0 = (const float*)d_in[6];
    const float* Wg[4] = {(const float*)d_in[7], (const float*)d_in[8], (const float*)d_in[9],
                          (const float*)d_in[10]};
    const float* L1w = (const float*)d_in[11];
    const float* L1b = (const float*)d_in[12];
    const float* L2w = (const float*)d_in[13];
    const float* L2b = (const float*)d_in[14];
    const float* L3w = (const float*)d_in[15];
    const float* L3b = (const float*)d_in[16];
    float* out = (float*)d_out;

    char* ws = (char*)d_ws;
    size_t off = 0;
    auto alloc = [&](size_t bytes) {
        void* p = ws + off;
        off = (off + bytes + 255) & ~(size_t)255;
        return p;
    };
    int* rp1 = (int*)alloc((NN + 1) * 4);
    int* cols1 = (int*)alloc(EE * 4);
    float* vals1 = (float*)alloc(EE * 4);
    int* rp2 = (int*)alloc((NN + 1) * 4);
    int* cols2 = (int*)alloc(EE * 4);
    float* vals2 = (float*)alloc(EE * 4);
    int* cntcur = (int*)alloc(4 * NN * 4);
    float* s1 = (float*)alloc(NN * 4);
    float* s2 = (float*)alloc(NN * 4);
    unsigned short* xh1 = (unsigned short*)alloc((size_t)NN * HD * 2);
    unsigned short* xh2 = (unsigned short*)alloc((size_t)NN * HD * 2);
    _Float16* xf1 = (_Float16*)alloc((size_t)NN * HD * 2);
    _Float16* xf2 = (_Float16*)alloc((size_t)NN * HD * 2);
    _Float16* w0h = (_Float16*)alloc((size_t)NN * HD * 2);
    short* zh1 = (short*)alloc((size_t)NN * HD * 2);
    short* zl1 = (short*)alloc((size_t)NN * HD * 2);
    short* zh2 = (short*)alloc((size_t)NN * HD * 2);
    short* zl2 = (short*)alloc((size_t)NN * HD * 2);
    short* W1p = (short*)alloc(16 * 4 * 512 * 2);
    short* W2p = (short*)alloc(16 * 8 * 512 * 2);
    short* Wgh[4];
    short* Wgl[4];
    for (int l = 0; l < 4; ++l) {
        Wgh[l] = (short*)alloc(8 * 4 * 512 * 2);
        Wgl[l] = (short*)alloc(8 * 4 * 512 * 2);
    }
    int* cnt = cntcur;
    int* cur = cntcur + 2 * NN;

    // ---- prep ----
    pack_all_kernel<<<112, 256, 0, stream>>>(L1w, W1p, L2w, W2p, Wg[0], Wg[1], Wg[2], Wg[3],
                                             Wgh[0], Wgl[0], Wgh[1], Wgl[1], Wgh[2], Wgl[2],
                                             Wgh[3], Wgl[3]);
    cvt_w0_kernel<<<(NN * HD / 8 + 255) / 256, 256, 0, stream>>>(W0, w0h);
    hipMemsetAsync(cntcur, 0, 4 * NN * 4, stream);
    hist2_kernel<<<(2 * EE + 255) / 256, 256, 0, stream>>>(row1, row2, cnt);
    scan2_kernel<<<2, 1024, 0, stream>>>(cnt, rp1, rp2);
    scatter2_kernel<<<(2 * EE + 255) / 256, 256, 0, stream>>>(
        row1, col1, val1, row2, col2, val2, rp1, rp2, cur, cols1, vals1, cols2, vals2);

    int spmm_grid = (2 * NN * 16 + 255) / 256;
    int ngrid = (NN + 63) / 64;
    spmm_norm_kernel<<<spmm_grid, 256, 0, stream>>>(rp1, cols1, vals1, rp2, cols2, vals2, w0h,
                                                    xf1, xh1, xf2, xh2);
    mlp_mfma_kernel<<<2 * ngrid, 256, 0, stream>>>(xh1, xh2, W1p, L1b, W2p, L2b, L3w, L3b, s1,
                                                   s2, ngrid);
    for (int l = 0; l < 4; ++l) {
        spmm_raw_kernel<<<spmm_grid, 256, 0, stream>>>(rp1, cols1, vals1, rp2, cols2, vals2,
                                                       xf1, xf2, zh1, zl1, zh2, zl2);
        gemm_mlp_kernel<<<2 * ngrid, 256, 0, stream>>>(zh1, zl1, zh2, zl2, Wgh[l], Wgl[l], W1p,
                                                       L1b, W2p, L2b, L3w, L3b, xf1, xf2, s1,
                                                       s2, ngrid, l < 3 ? 1 : 0, l < 3 ? 1 : 0);
    }

    final_kernel<<<(NN + 255) / 256, 256, 0, stream>>>(s1, s2, out);
}

// Round 10
// 505.524 us; speedup vs baseline: 1.4365x; 1.3110x over previous
//
#include <hip/hip_runtime.h>

#define NN 50000
#define EE 250000
#define HD 128

typedef __attribute__((ext_vector_type(8))) _Float16 f16x8;
typedef __attribute__((ext_vector_type(4))) _Float16 f16x4;
typedef __attribute__((ext_vector_type(4))) float f32x4;

// ---------------- CSR build (both graphs in one launch) ----------------
__global__ void hist2_kernel(const int* __restrict__ row1, const int* __restrict__ row2,
                             int* __restrict__ cnt) {
    int t = blockIdx.x * blockDim.x + threadIdx.x;
    if (t >= 2 * EE) return;
    int g = t >= EE;
    int e = t - g * EE;
    const int* row = g ? row2 : row1;
    atomicAdd(&cnt[g * NN + row[e]], 1);
}

__global__ __launch_bounds__(1024) void scan2_kernel(const int* __restrict__ cnt_all,
                                                     int* __restrict__ rp1,
                                                     int* __restrict__ rp2) {
    __shared__ int s[1024];
    const int* cnt = cnt_all + blockIdx.x * NN;
    int* rp = blockIdx.x ? rp2 : rp1;
    int tid = threadIdx.x;
    int c0 = 0;
    for (int base = 0; base < NN; base += 8192) {
        int v[8];
        int sum = 0;
        int i0 = base + tid * 8;
#pragma unroll
        for (int j = 0; j < 8; ++j) {
            int i = i0 + j;
            v[j] = (i < NN) ? cnt[i] : 0;
            sum += v[j];
        }
        s[tid] = sum;
        __syncthreads();
        for (int off = 1; off < 1024; off <<= 1) {
            int t2 = (tid >= off) ? s[tid - off] : 0;
            __syncthreads();
            s[tid] += t2;
            __syncthreads();
        }
        int excl = c0 + s[tid] - sum;
#pragma unroll
        for (int j = 0; j < 8; ++j) {
            int i = i0 + j;
            if (i < NN) rp[i] = excl;
            excl += v[j];
        }
        int tot = s[1023];
        __syncthreads();
        c0 += tot;
    }
    if (tid == 0) rp[NN] = c0;
}

// stores interleaved (col, val-bits) per edge: 1 load/edge in spmm
__global__ void scatter2_kernel(const int* __restrict__ row1, const int* __restrict__ col1,
                                const float* __restrict__ val1, const int* __restrict__ row2,
                                const int* __restrict__ col2, const float* __restrict__ val2,
                                const int* __restrict__ rp1, const int* __restrict__ rp2,
                                int* __restrict__ cur, int2* __restrict__ ev1,
                                int2* __restrict__ ev2) {
    int t = blockIdx.x * blockDim.x + threadIdx.x;
    if (t >= 2 * EE) return;
    int g = t >= EE;
    int e = t - g * EE;
    const int* row = g ? row2 : row1;
    const int* col = g ? col2 : col1;
    const float* val = g ? val2 : val1;
    const int* rp = g ? rp2 : rp1;
    int2* ev = g ? ev2 : ev1;
    int r = row[e];
    int p = atomicAdd(&cur[g * NN + r], 1);
    int d = rp[r] + p;
    ev[d] = make_int2(col[e], __builtin_bit_cast(int, val[e]));
}

// ---------------- weight pack (fp16, MFMA fragment order, one launch) ----------------
__device__ inline void pack_one(const float* __restrict__ in, _Float16* __restrict__ out,
                                int NCOL, int NKS, int t) {
    int lane = t & 63, f = t >> 6;
    int ks = f % NKS, ct = f / NKS;
    int nl = lane & 15, kg = lane >> 4;
    int c = ct * 16 + nl;
    f16x8 o;
#pragma unroll
    for (int j = 0; j < 8; ++j) {
        int k = ks * 32 + kg * 8 + j;
        o[j] = (_Float16)in[k * NCOL + c];
    }
    *(f16x8*)(out + f * 512 + lane * 8) = o;
}

__global__ void pack_all_kernel(const float* __restrict__ L1w, _Float16* __restrict__ W1p,
                                const float* __restrict__ L2w, _Float16* __restrict__ W2p,
                                const float* __restrict__ Wg0, const float* __restrict__ Wg1,
                                const float* __restrict__ Wg2, const float* __restrict__ Wg3,
                                _Float16* __restrict__ Wp0, _Float16* __restrict__ Wp1,
                                _Float16* __restrict__ Wp2, _Float16* __restrict__ Wp3) {
    int t = blockIdx.x * 256 + threadIdx.x;
    if (t < 4096) {
        pack_one(L1w, W1p, 256, 4, t);
    } else if (t < 12288) {
        pack_one(L2w, W2p, 256, 8, t - 4096);
    } else if (t < 20480) {
        int u = t - 12288;
        int l = u >> 11;  // 2048 per layer
        int tt = u & 2047;
        const float* in = l == 0 ? Wg0 : l == 1 ? Wg1 : l == 2 ? Wg2 : Wg3;
        _Float16* out = l == 0 ? Wp0 : l == 1 ? Wp1 : l == 2 ? Wp2 : Wp3;
        pack_one(in, out, 128, 4, tt);
    }
}

__global__ void cvt_w0_kernel(const float* __restrict__ in, _Float16* __restrict__ out) {
    int t = blockIdx.x * 256 + threadIdx.x;
    int i = t * 8;
    if (i >= NN * HD) return;
    float4 a = *(const float4*)(in + i);
    float4 b = *(const float4*)(in + i + 4);
    f16x8 h;
    h[0] = (_Float16)a.x; h[1] = (_Float16)a.y; h[2] = (_Float16)a.z; h[3] = (_Float16)a.w;
    h[4] = (_Float16)b.x; h[5] = (_Float16)b.y; h[6] = (_Float16)b.z; h[7] = (_Float16)b.w;
    *(f16x8*)(out + i) = h;
}

// ---------------- SpMM layer-1 (both graphs): xf = l2norm(relu(A @ W0h)) ----------------
// 4 rows/wave, 16 lanes x fp16x8 (16B/lane); edge loop unrolled x8 branch-free.
__global__ __launch_bounds__(256) void spmm_norm_kernel(
    const int* __restrict__ rp1, const int2* __restrict__ ev1, const int* __restrict__ rp2,
    const int2* __restrict__ ev2, const _Float16* __restrict__ xin,
    _Float16* __restrict__ xf1, _Float16* __restrict__ xf2) {
    int rr = (blockIdx.x * 256 + threadIdx.x) >> 4;
    int ln = threadIdx.x & 15;
    if (rr >= 2 * NN) return;
    int g = rr >= NN;
    int r = rr - g * NN;
    const int* rp = g ? rp2 : rp1;
    const int2* ev = g ? ev2 : ev1;
    _Float16* xf = g ? xf2 : xf1;
    int beg = rp[r], end = rp[r + 1];
    float acc[8] = {};
    for (int e = beg; e < end; e += 8) {
#pragma unroll
        for (int i = 0; i < 8; ++i) {
            int ei = e + i;
            int idx = ei < end ? ei : end - 1;
            int2 cv = ev[idx];
            float v = ei < end ? __builtin_bit_cast(float, cv.y) : 0.f;
            f16x8 xr = *(const f16x8*)(xin + (size_t)cv.x * HD + ln * 8);
#pragma unroll
            for (int j = 0; j < 8; ++j) acc[j] = fmaf(v, (float)xr[j], acc[j]);
        }
    }
    float ss = 0.f;
#pragma unroll
    for (int j = 0; j < 8; ++j) {
        acc[j] = fmaxf(acc[j], 0.f);
        ss = fmaf(acc[j], acc[j], ss);
    }
#pragma unroll
    for (int off = 1; off < 16; off <<= 1) ss += __shfl_xor(ss, off, 64);
    float sc = 1.f / fmaxf(sqrtf(ss), 1e-12f);
    f16x8 hf;
#pragma unroll
    for (int j = 0; j < 8; ++j) hf[j] = (_Float16)(acc[j] * sc);
    *(f16x8*)(xf + (size_t)r * HD + ln * 8) = hf;
}

// ---------------- SpMM raw (both graphs): z = A @ xf16 (fp16 out) ----------------
__global__ __launch_bounds__(256) void spmm_raw_kernel(
    const int* __restrict__ rp1, const int2* __restrict__ ev1, const int* __restrict__ rp2,
    const int2* __restrict__ ev2, const _Float16* __restrict__ xf1,
    const _Float16* __restrict__ xf2, _Float16* __restrict__ z1, _Float16* __restrict__ z2) {
    int rr = (blockIdx.x * 256 + threadIdx.x) >> 4;
    int ln = threadIdx.x & 15;
    if (rr >= 2 * NN) return;
    int g = rr >= NN;
    int r = rr - g * NN;
    const int* rp = g ? rp2 : rp1;
    const int2* ev = g ? ev2 : ev1;
    const _Float16* xin = g ? xf2 : xf1;
    _Float16* z = g ? z2 : z1;
    int beg = rp[r], end = rp[r + 1];
    float acc[8] = {};
    for (int e = beg; e < end; e += 8) {
#pragma unroll
        for (int i = 0; i < 8; ++i) {
            int ei = e + i;
            int idx = ei < end ? ei : end - 1;
            int2 cv = ev[idx];
            float v = ei < end ? __builtin_bit_cast(float, cv.y) : 0.f;
            f16x8 xr = *(const f16x8*)(xin + (size_t)cv.x * HD + ln * 8);
#pragma unroll
            for (int j = 0; j < 8; ++j) acc[j] = fmaf(v, (float)xr[j], acc[j]);
        }
    }
    f16x8 h;
#pragma unroll
    for (int j = 0; j < 8; ++j) h[j] = (_Float16)acc[j];
    *(f16x8*)(z + (size_t)r * HD + ln * 8) = h;
}

// ---------------- fused GEMM + MLP (fp16 MFMA, both graphs in one grid) ----------------
__global__ __launch_bounds__(256, 2) void gemm_mlp_kernel(
    const _Float16* __restrict__ z1, const _Float16* __restrict__ z2,
    const _Float16* __restrict__ Wp, const _Float16* __restrict__ W1p,
    const float* __restrict__ L1b, const _Float16* __restrict__ W2p,
    const float* __restrict__ L2b, const float* __restrict__ L3w,
    const float* __restrict__ L3b, _Float16* __restrict__ xf1, _Float16* __restrict__ xf2,
    float* __restrict__ s1, float* __restrict__ s2, int ngrid, int do_norm, int write_x) {
    __shared__ __align__(16) char U[32768];  // Xt (16KB) then reused as H1s (32KB)
    __shared__ float redss[4][64];
    __shared__ float red[4][64];
    char* Xt = U;
    char* H1s = U;
    int tid = threadIdx.x;
    int wave = tid >> 6, lane = tid & 63;
    int nl = lane & 15, kg = lane >> 4;
    int g = blockIdx.x >= ngrid;
    int tile = (blockIdx.x - g * ngrid) * 64;
    const _Float16* z = g ? z2 : z1;
    _Float16* xfout = g ? xf2 : xf1;
    float* score = g ? s2 : s1;

    // ===== GEMM phase: x = [l2norm](relu(z @ W)) =====
    f16x8 ah[4][4];
#pragma unroll
    for (int m = 0; m < 4; ++m) {
        int node = tile + m * 16 + nl;
        if (node >= NN) node = NN - 1;
        const _Float16* ph = z + (size_t)node * HD + kg * 8;
#pragma unroll
        for (int ks = 0; ks < 4; ++ks) ah[m][ks] = *(const f16x8*)(ph + ks * 32);
    }

    f32x4 acc[2][4];
#pragma unroll
    for (int c = 0; c < 2; ++c) {
        int ct = wave * 2 + c;
        f16x8 wh[4];
#pragma unroll
        for (int ks = 0; ks < 4; ++ks)
            wh[ks] = *(const f16x8*)(Wp + (ct * 4 + ks) * 512 + lane * 8);
#pragma unroll
        for (int m = 0; m < 4; ++m) acc[c][m] = (f32x4){0.f, 0.f, 0.f, 0.f};
#pragma unroll
        for (int ks = 0; ks < 4; ++ks)
#pragma unroll
            for (int m = 0; m < 4; ++m)
                acc[c][m] = __builtin_amdgcn_mfma_f32_16x16x32_f16(wh[ks], ah[m][ks], acc[c][m], 0, 0, 0);
    }
#pragma unroll
    for (int c = 0; c < 2; ++c)
#pragma unroll
        for (int m = 0; m < 4; ++m)
#pragma unroll
            for (int r = 0; r < 4; ++r) acc[c][m][r] = fmaxf(acc[c][m][r], 0.f);

    float scale[4] = {1.f, 1.f, 1.f, 1.f};
    if (do_norm) {
        float ss[4];
#pragma unroll
        for (int m = 0; m < 4; ++m) {
            float s = 0.f;
#pragma unroll
            for (int c = 0; c < 2; ++c)
#pragma unroll
                for (int r = 0; r < 4; ++r) s = fmaf(acc[c][m][r], acc[c][m][r], s);
            s += __shfl_xor(s, 16, 64);
            s += __shfl_xor(s, 32, 64);
            ss[m] = s;
        }
        if (kg == 0) {
#pragma unroll
            for (int m = 0; m < 4; ++m) redss[wave][m * 16 + nl] = ss[m];
        }
        __syncthreads();
#pragma unroll
        for (int m = 0; m < 4; ++m) {
            int r = m * 16 + nl;
            float tot = redss[0][r] + redss[1][r] + redss[2][r] + redss[3][r];
            scale[m] = 1.f / fmaxf(sqrtf(tot), 1e-12f);
        }
    }

    // x-tile to LDS (fp16, swizzled, stride 256B) + fp16 global
#pragma unroll
    for (int c = 0; c < 2; ++c) {
        int ct = wave * 2 + c;
#pragma unroll
        for (int m = 0; m < 4; ++m) {
            f16x4 hs;
            hs[0] = (_Float16)(acc[c][m][0] * scale[m]);
            hs[1] = (_Float16)(acc[c][m][1] * scale[m]);
            hs[2] = (_Float16)(acc[c][m][2] * scale[m]);
            hs[3] = (_Float16)(acc[c][m][3] * scale[m]);
            int r = m * 16 + nl;
            int byte = (r * 256 + ct * 32 + kg * 8) ^ ((r & 7) << 4);
            *(f16x4*)(Xt + byte) = hs;
            int node = tile + r;
            if (write_x && node < NN)
                *(f16x4*)(xfout + (size_t)node * HD + ct * 16 + kg * 4) = hs;
        }
    }
    __syncthreads();

    // ===== MLP phase =====
    f16x8 a1[4][4];
#pragma unroll
    for (int m = 0; m < 4; ++m) {
        int r = m * 16 + nl;
#pragma unroll
        for (int ks = 0; ks < 4; ++ks) {
            int byte = (r * 256 + ks * 64 + kg * 16) ^ ((r & 7) << 4);
            a1[m][ks] = *(const f16x8*)(Xt + byte);
        }
    }
    __syncthreads();  // all A1 reads done before H1s overwrites the union

#pragma unroll
    for (int c = 0; c < 4; ++c) {
        int ct = wave * 4 + c;
        f16x8 w[4];
#pragma unroll
        for (int ks = 0; ks < 4; ++ks)
            w[ks] = *(const f16x8*)(W1p + (ct * 4 + ks) * 512 + lane * 8);
        f32x4 a[4];
#pragma unroll
        for (int m = 0; m < 4; ++m) a[m] = (f32x4){0.f, 0.f, 0.f, 0.f};
#pragma unroll
        for (int ks = 0; ks < 4; ++ks)
#pragma unroll
            for (int m = 0; m < 4; ++m)
                a[m] = __builtin_amdgcn_mfma_f32_16x16x32_f16(w[ks], a1[m][ks], a[m], 0, 0, 0);
        float4 b1v = *(const float4*)(L1b + ct * 16 + kg * 4);
#pragma unroll
        for (int m = 0; m < 4; ++m) {
            f16x4 hs;
            hs[0] = (_Float16)fmaxf(a[m][0] + b1v.x, 0.f);
            hs[1] = (_Float16)fmaxf(a[m][1] + b1v.y, 0.f);
            hs[2] = (_Float16)fmaxf(a[m][2] + b1v.z, 0.f);
            hs[3] = (_Float16)fmaxf(a[m][3] + b1v.w, 0.f);
            int r = m * 16 + nl;
            int byte = (r * 512 + ct * 32 + kg * 8) ^ ((r & 7) << 4);
            *(f16x4*)(H1s + byte) = hs;
        }
    }
    __syncthreads();

    f16x8 a2[4][8];
#pragma unroll
    for (int m = 0; m < 4; ++m) {
        int r = m * 16 + nl;
#pragma unroll
        for (int ks = 0; ks < 8; ++ks) {
            int byte = (r * 512 + ks * 64 + kg * 16) ^ ((r & 7) << 4);
            a2[m][ks] = *(const f16x8*)(H1s + byte);
        }
    }

    float t[4] = {0.f, 0.f, 0.f, 0.f};
#pragma unroll
    for (int c = 0; c < 4; ++c) {
        int ct = wave * 4 + c;
        f16x8 w[8];
#pragma unroll
        for (int ks = 0; ks < 8; ++ks)
            w[ks] = *(const f16x8*)(W2p + (ct * 8 + ks) * 512 + lane * 8);
        f32x4 a[4];
#pragma unroll
        for (int m = 0; m < 4; ++m) a[m] = (f32x4){0.f, 0.f, 0.f, 0.f};
#pragma unroll
        for (int ks = 0; ks < 8; ++ks)
#pragma unroll
            for (int m = 0; m < 4; ++m)
                a[m] = __builtin_amdgcn_mfma_f32_16x16x32_f16(w[ks], a2[m][ks], a[m], 0, 0, 0);
        float4 b2v = *(const float4*)(L2b + ct * 16 + kg * 4);
        float4 w3v = *(const float4*)(L3w + ct * 16 + kg * 4);
#pragma unroll
        for (int m = 0; m < 4; ++m) {
            t[m] = fmaf(fmaxf(a[m][0] + b2v.x, 0.f), w3v.x, t[m]);
            t[m] = fmaf(fmaxf(a[m][1] + b2v.y, 0.f), w3v.y, t[m]);
            t[m] = fmaf(fmaxf(a[m][2] + b2v.z, 0.f), w3v.z, t[m]);
            t[m] = fmaf(fmaxf(a[m][3] + b2v.w, 0.f), w3v.w, t[m]);
        }
    }
#pragma unroll
    for (int m = 0; m < 4; ++m) {
        t[m] += __shfl_xor(t[m], 16, 64);
        t[m] += __shfl_xor(t[m], 32, 64);
    }
    if (kg == 0) {
#pragma unroll
        for (int m = 0; m < 4; ++m) red[wave][m * 16 + nl] = t[m];
    }
    __syncthreads();
    if (tid < 64) {
        int gg = tile + tid;
        if (gg < NN) {
            float s = red[0][tid] + red[1][tid] + red[2][tid] + red[3][tid];
            score[gg] += s + L3b[0];
        }
    }
}

// ---------------- standalone MLP (layer-1 path, both graphs), score = ----------------
__global__ __launch_bounds__(256, 2) void mlp_mfma_kernel(
    const _Float16* __restrict__ xf1, const _Float16* __restrict__ xf2,
    const _Float16* __restrict__ W1p, const float* __restrict__ L1b,
    const _Float16* __restrict__ W2p, const float* __restrict__ L2b,
    const float* __restrict__ L3w, const float* __restrict__ L3b, float* __restrict__ s1,
    float* __restrict__ s2, int ngrid) {
    __shared__ __align__(16) char H1s[32768];
    __shared__ float red[4][64];
    int tid = threadIdx.x;
    int wave = tid >> 6, lane = tid & 63;
    int nl = lane & 15, kg = lane >> 4;
    int g = blockIdx.x >= ngrid;
    int tile = (blockIdx.x - g * ngrid) * 64;
    const _Float16* xf = g ? xf2 : xf1;
    float* score = g ? s2 : s1;

    f16x8 a1[4][4];
#pragma unroll
    for (int m = 0; m < 4; ++m) {
        int node = tile + m * 16 + nl;
        if (node >= NN) node = NN - 1;
        const _Float16* xr = xf + (size_t)node * HD + kg * 8;
#pragma unroll
        for (int ks = 0; ks < 4; ++ks) a1[m][ks] = *(const f16x8*)(xr + ks * 32);
    }

#pragma unroll
    for (int c = 0; c < 4; ++c) {
        int ct = wave * 4 + c;
        f16x8 w[4];
#pragma unroll
        for (int ks = 0; ks < 4; ++ks)
            w[ks] = *(const f16x8*)(W1p + (ct * 4 + ks) * 512 + lane * 8);
        f32x4 a[4];
#pragma unroll
        for (int m = 0; m < 4; ++m) a[m] = (f32x4){0.f, 0.f, 0.f, 0.f};
#pragma unroll
        for (int ks = 0; ks < 4; ++ks)
#pragma unroll
            for (int m = 0; m < 4; ++m)
                a[m] = __builtin_amdgcn_mfma_f32_16x16x32_f16(w[ks], a1[m][ks], a[m], 0, 0, 0);
        float4 b1v = *(const float4*)(L1b + ct * 16 + kg * 4);
#pragma unroll
        for (int m = 0; m < 4; ++m) {
            f16x4 hs;
            hs[0] = (_Float16)fmaxf(a[m][0] + b1v.x, 0.f);
            hs[1] = (_Float16)fmaxf(a[m][1] + b1v.y, 0.f);
            hs[2] = (_Float16)fmaxf(a[m][2] + b1v.z, 0.f);
            hs[3] = (_Float16)fmaxf(a[m][3] + b1v.w, 0.f);
            int r = m * 16 + nl;
            int byte = (r * 512 + ct * 32 + kg * 8) ^ ((r & 7) << 4);
            *(f16x4*)(H1s + byte) = hs;
        }
    }
    __syncthreads();

    f16x8 a2[4][8];
#pragma unroll
    for (int m = 0; m < 4; ++m) {
        int r = m * 16 + nl;
#pragma unroll
        for (int ks = 0; ks < 8; ++ks) {
            int byte = (r * 512 + ks * 64 + kg * 16) ^ ((r & 7) << 4);
            a2[m][ks] = *(const f16x8*)(H1s + byte);
        }
    }

    float t[4] = {0.f, 0.f, 0.f, 0.f};
#pragma unroll
    for (int c = 0; c < 4; ++c) {
        int ct = wave * 4 + c;
        f16x8 w[8];
#pragma unroll
        for (int ks = 0; ks < 8; ++ks)
            w[ks] = *(const f16x8*)(W2p + (ct * 8 + ks) * 512 + lane * 8);
        f32x4 a[4];
#pragma unroll
        for (int m = 0; m < 4; ++m) a[m] = (f32x4){0.f, 0.f, 0.f, 0.f};
#pragma unroll
        for (int ks = 0; ks < 8; ++ks)
#pragma unroll
            for (int m = 0; m < 4; ++m)
                a[m] = __builtin_amdgcn_mfma_f32_16x16x32_f16(w[ks], a2[m][ks], a[m], 0, 0, 0);
        float4 b2v = *(const float4*)(L2b + ct * 16 + kg * 4);
        float4 w3v = *(const float4*)(L3w + ct * 16 + kg * 4);
#pragma unroll
        for (int m = 0; m < 4; ++m) {
            t[m] = fmaf(fmaxf(a[m][0] + b2v.x, 0.f), w3v.x, t[m]);
            t[m] = fmaf(fmaxf(a[m][1] + b2v.y, 0.f), w3v.y, t[m]);
            t[m] = fmaf(fmaxf(a[m][2] + b2v.z, 0.f), w3v.z, t[m]);
            t[m] = fmaf(fmaxf(a[m][3] + b2v.w, 0.f), w3v.w, t[m]);
        }
    }
#pragma unroll
    for (int m = 0; m < 4; ++m) {
        t[m] += __shfl_xor(t[m], 16, 64);
        t[m] += __shfl_xor(t[m], 32, 64);
    }
    if (kg == 0) {
#pragma unroll
        for (int m = 0; m < 4; ++m) red[wave][m * 16 + nl] = t[m];
    }
    __syncthreads();
    if (tid < 64) {
        int gg = tile + tid;
        if (gg < NN) {
            float s = red[0][tid] + red[1][tid] + red[2][tid] + red[3][tid];
            score[gg] = s + L3b[0];  // first MLP writes (no memset needed)
        }
    }
}

__global__ void final_kernel(const float* __restrict__ s1, const float* __restrict__ s2,
                             float* __restrict__ out) {
    int i = blockIdx.x * blockDim.x + threadIdx.x;
    if (i < NN) out[i] = s1[i] * s2[i];
}

extern "C" void kernel_launch(void* const* d_in, const int* in_sizes, int n_in,
                              void* d_out, int out_size, void* d_ws, size_t ws_size,
                              hipStream_t stream) {
    const int* row1 = (const int*)d_in[0];
    const int* col1 = (const int*)d_in[1];
    const float* val1 = (const float*)d_in[2];
    const int* row2 = (const int*)d_in[3];
    const int* col2 = (const int*)d_in[4];
    const float* val2 = (const float*)d_in[5];
    const float* W0 = (const float*)d_in[6];
    const float* Wg[4] = {(const float*)d_in[7], (const float*)d_in[8], (const float*)d_in[9],
                          (const float*)d_in[10]};
    const float* L1w = (const float*)d_in[11];
    const float* L1b = (const float*)d_in[12];
    const float* L2w = (const float*)d_in[13];
    const float* L2b = (const float*)d_in[14];
    const float* L3w = (const float*)d_in[15];
    const float* L3b = (const float*)d_in[16];
    float* out = (float*)d_out;

    char* ws = (char*)d_ws;
    size_t off = 0;
    auto alloc = [&](size_t bytes) {
        void* p = ws + off;
        off = (off + bytes + 255) & ~(size_t)255;
        return p;
    };
    int* rp1 = (int*)alloc((NN + 1) * 4);
    int* rp2 = (int*)alloc((NN + 1) * 4);
    int2* ev1 = (int2*)alloc((size_t)EE * 8);
    int2* ev2 = (int2*)alloc((size_t)EE * 8);
    int* cntcur = (int*)alloc(4 * NN * 4);
    float* s1 = (float*)alloc(NN * 4);
    float* s2 = (float*)alloc(NN * 4);
    _Float16* xf1 = (_Float16*)alloc((size_t)NN * HD * 2);
    _Float16* xf2 = (_Float16*)alloc((size_t)NN * HD * 2);
    _Float16* w0h = (_Float16*)alloc((size_t)NN * HD * 2);
    _Float16* z1 = (_Float16*)alloc((size_t)NN * HD * 2);
    _Float16* z2 = (_Float16*)alloc((size_t)NN * HD * 2);
    _Float16* W1p = (_Float16*)alloc(16 * 4 * 512 * 2);
    _Float16* W2p = (_Float16*)alloc(16 * 8 * 512 * 2);
    _Float16* Wp[4];
    for (int l = 0; l < 4; ++l) Wp[l] = (_Float16*)alloc(8 * 4 * 512 * 2);
    int* cnt = cntcur;
    int* cur = cntcur + 2 * NN;

    // ---- prep ----
    pack_all_kernel<<<80, 256, 0, stream>>>(L1w, W1p, L2w, W2p, Wg[0], Wg[1], Wg[2], Wg[3],
                                            Wp[0], Wp[1], Wp[2], Wp[3]);
    cvt_w0_kernel<<<(NN * HD / 8 + 255) / 256, 256, 0, stream>>>(W0, w0h);
    hipMemsetAsync(cntcur, 0, 4 * NN * 4, stream);
    hist2_kernel<<<(2 * EE + 255) / 256, 256, 0, stream>>>(row1, row2, cnt);
    scan2_kernel<<<2, 1024, 0, stream>>>(cnt, rp1, rp2);
    scatter2_kernel<<<(2 * EE + 255) / 256, 256, 0, stream>>>(row1, col1, val1, row2, col2,
                                                              val2, rp1, rp2, cur, ev1, ev2);

    int spmm_grid = (2 * NN * 16 + 255) / 256;
    int ngrid = (NN + 63) / 64;
    spmm_norm_kernel<<<spmm_grid, 256, 0, stream>>>(rp1, ev1, rp2, ev2, w0h, xf1, xf2);
    mlp_mfma_kernel<<<2 * ngrid, 256, 0, stream>>>(xf1, xf2, W1p, L1b, W2p, L2b, L3w, L3b, s1,
                                                   s2, ngrid);
    for (int l = 0; l < 4; ++l) {
        spmm_raw_kernel<<<spmm_grid, 256, 0, stream>>>(rp1, ev1, rp2, ev2, xf1, xf2, z1, z2);
        gemm_mlp_kernel<<<2 * ngrid, 256, 0, stream>>>(z1, z2, Wp[l], W1p, L1b, W2p, L2b, L3w,
                                                       L3b, xf1, xf2, s1, s2, ngrid,
                                                       l < 3 ? 1 : 0, l < 3 ? 1 : 0);
    }

    final_kernel<<<(NN + 255) / 256, 256, 0, stream>>>(s1, s2, out);
}